// Round 26
// baseline (23.009 us; speedup 1.0000x reference)
//
#include <hip/hip_runtime.h>

#define SEQ 2048
#define DIM 6
#define NSEG 8               // prep segments per batch
#define SEGR (SEQ / NSEG)    // 256 rows per prep block
#define VROW 2056            // padded LDS V^T row stride
#define CH 8                 // t-tiles per statically-unrolled chunk

typedef _Float16 half4F __attribute__((ext_vector_type(4)));
typedef short bf16x4 __attribute__((ext_vector_type(4)));
typedef float f32x4 __attribute__((ext_vector_type(4)));

union FragU { uint2 u; half4F h; bf16x4 b; };

__device__ __forceinline__ unsigned pkh(float a, float b) {
    return __builtin_bit_cast(unsigned, __builtin_amdgcn_cvt_pkrtz(a, b));
}
__device__ __forceinline__ unsigned bf16rn(float x) {  // RNE (finite inputs)
    unsigned u = __builtin_bit_cast(unsigned, x);
    return (u + 0x7FFFu + ((u >> 16) & 1u)) >> 16;
}
__device__ __forceinline__ unsigned pkbf(float a, float b) {
    return bf16rn(a) | (bf16rn(b) << 16);
}
// Packed truncating f32->bf16 pair (P only): ONE v_perm_b32.
__device__ __forceinline__ unsigned pkbf_trunc(float a, float b) {
    return __builtin_amdgcn_perm(__builtin_bit_cast(unsigned, b),
                                 __builtin_bit_cast(unsigned, a),
                                 0x07060302u);
}

__device__ __forceinline__ f32x4 mfma_bf16_(bf16x4 a, bf16x4 b, f32x4 c) {
#if __has_builtin(__builtin_amdgcn_mfma_f32_16x16x16bf16_1k)
    return __builtin_amdgcn_mfma_f32_16x16x16bf16_1k(a, b, c, 0, 0, 0);
#else
    f32x4 d;
    asm("v_mfma_f32_16x16x16_bf16 %0, %1, %2, %3"
        : "=v"(d) : "v"(a), "v"(b), "v"(c));
    return d;
#endif
}

// ws: Kc [B][SEQ][8] fp16 | Vc [B][SEQ][8] bf16 | rowl [B][SEQ] u16 |
//     vsumP [B][NSEG][8] f32 | nuArr [B] int
// Masked cols excluded (exact: ref weight underflows to 0).
// Masked rows = mean(V over ALL t) (f32-exact).

__launch_bounds__(256)
__global__ void prep(const float* __restrict__ X, const int* __restrict__ mask,
                     const float* __restrict__ Wk, const float* __restrict__ bk,
                     const float* __restrict__ Wv, const float* __restrict__ bv,
                     __fp16* __restrict__ Kc, unsigned short* __restrict__ Vc,
                     unsigned short* __restrict__ rowl,
                     float* __restrict__ vsumP, int* __restrict__ nuArr) {
    __shared__ unsigned char msk[SEQ];
    __shared__ int wexcl[256];
    __shared__ int wtot[4];
    __shared__ float vred[4][8];
    const int b = blockIdx.x >> 3, seg = blockIdx.x & 7;
    const int tid = threadIdx.x;
    const int lane = tid & 63, wid = tid >> 6;
    const int* mb = mask + (size_t)b * SEQ;
    const float L2E = 1.44269504088896f;

    int cnt = 0;
#pragma unroll
    for (int j = 0; j < 8; ++j) {
        const int m = (mb[tid * 8 + j] != 0);
        msk[tid * 8 + j] = (unsigned char)m;
        cnt += m;
    }
    int inc = cnt;
#pragma unroll
    for (int off = 1; off < 64; off <<= 1) {
        const int t2 = __shfl_up(inc, off);
        if (lane >= off) inc += t2;
    }
    wexcl[tid] = inc - cnt;
    if (lane == 63) wtot[wid] = inc;
    __syncthreads();
    const int Nu = wtot[0] + wtot[1] + wtot[2] + wtot[3];
    if (seg == 0 && tid == 0) nuArr[b] = Nu;

    const int t = seg * SEGR + tid;
    const int i8 = t >> 3;
    int slot = wexcl[i8];
    {
        const int w = i8 >> 6;
        if (w > 0) slot += wtot[0];
        if (w > 1) slot += wtot[1];
        if (w > 2) slot += wtot[2];
    }
    for (int j = i8 * 8; j < t; ++j) slot += msk[j];

    const float2* xp = reinterpret_cast<const float2*>(X + ((size_t)b * SEQ + t) * DIM);
    float2 x01 = xp[0], x23 = xp[1], x45 = xp[2];
    float x[DIM] = {x01.x, x01.y, x23.x, x23.y, x45.x, x45.y};
    float kk[DIM], vv[DIM];
#pragma unroll
    for (int r = 0; r < DIM; ++r) {
        float k = bk[r], v = bv[r];
#pragma unroll
        for (int c = 0; c < DIM; ++c) {
            k = fmaf(Wk[r * DIM + c], x[c], k);
            v = fmaf(Wv[r * DIM + c], x[c], v);
        }
        kk[r] = k * L2E;
        vv[r] = v;
    }
    if (msk[t]) {
        uint4 kw;
        kw.x = pkh(kk[0], kk[1]);
        kw.y = pkh(kk[2], kk[3]);
        kw.z = pkh(kk[4], kk[5]);
        kw.w = 0u;  // bias 0: compacted cols are all unmasked
        *reinterpret_cast<uint4*>(Kc + ((size_t)b * SEQ + slot) * 8) = kw;
        uint4 vw;
        vw.x = pkbf(vv[0], vv[1]);
        vw.y = pkbf(vv[2], vv[3]);
        vw.z = pkbf(vv[4], vv[5]);
        vw.w = 0u;
        *reinterpret_cast<uint4*>(Vc + ((size_t)b * SEQ + slot) * 8) = vw;
        rowl[(size_t)b * SEQ + slot] = (unsigned short)t;
    }

#pragma unroll
    for (int r = 0; r < DIM; ++r) {
        float s = vv[r];
#pragma unroll
        for (int off = 1; off < 64; off <<= 1) s += __shfl_xor(s, off);
        if (lane == 0) vred[wid][r] = s;
    }
    __syncthreads();
    if (tid < DIM) {
        vsumP[((size_t)b * NSEG + seg) * 8 + tid] =
            vred[0][tid] + vred[1][tid] + vred[2][tid] + vred[3][tid];
    }
}

__launch_bounds__(512, 2)
__global__ void attn_mfma(const float* __restrict__ X,
                          const int* __restrict__ mask,
                          const float* __restrict__ Wq, const float* __restrict__ bq,
                          const __fp16* __restrict__ Kc,
                          const unsigned short* __restrict__ Vc,
                          const unsigned short* __restrict__ rowl,
                          const float* __restrict__ vsumP,
                          const int* __restrict__ nuArr,
                          float* __restrict__ out) {
    __shared__ __align__(16) __fp16 Ksm[SEQ * 8];          // 32 KB
    __shared__ __align__(16) unsigned short Vt[7 * VROW];  // 28.8 KB

    const int b = blockIdx.x >> 4, blk = blockIdx.x & 15;
    const int tid = threadIdx.x;
    const int Nu = nuArr[b];
    // pad compacted columns to a multiple of CH*16 so the main loop has a
    // statically-unrolled body (pads: bias -1024 -> p == 0 exactly, V = 0)
    const int NTC = (Nu + CH * 16 - 1) & ~(CH * 16 - 1);

    // masked-row fill for original rows [blk*128, +128): meanV (f32-exact)
    if (tid < 128) {
        const int t = blk * 128 + tid;
        if (mask[(size_t)b * SEQ + t] == 0) {
            float* o = out + ((size_t)b * SEQ + t) * DIM;
#pragma unroll
            for (int r = 0; r < DIM; ++r) {
                float s = 0.0f;
#pragma unroll
                for (int g2 = 0; g2 < NSEG; ++g2)
                    s += vsumP[((size_t)b * NSEG + g2) * 8 + r];
                o[r] = s * (1.0f / SEQ);
            }
        }
    }

    const int rowbase = blk * 128;
    if (rowbase >= Nu) return;  // fill-only block

    // bulk-stage compacted K'/V' from L2; V transposed into LDS rows
    const uint4* kg = reinterpret_cast<const uint4*>(Kc + (size_t)b * SEQ * 8);
    const uint4* vg = reinterpret_cast<const uint4*>(Vc + (size_t)b * SEQ * 8);
    for (int i = tid; i < NTC; i += 512) {
        uint4 kw, vw;
        if (i < Nu) { kw = kg[i]; vw = vg[i]; }
        else { kw = make_uint4(0, 0, 0, pkh(-1024.0f, 0.0f)); vw = make_uint4(0, 0, 0, 0); }
        reinterpret_cast<uint4*>(Ksm)[i] = kw;
        Vt[0 * VROW + i] = (unsigned short)(vw.x & 0xFFFFu);
        Vt[1 * VROW + i] = (unsigned short)(vw.x >> 16);
        Vt[2 * VROW + i] = (unsigned short)(vw.y & 0xFFFFu);
        Vt[3 * VROW + i] = (unsigned short)(vw.y >> 16);
        Vt[4 * VROW + i] = (unsigned short)(vw.z & 0xFFFFu);
        Vt[5 * VROW + i] = (unsigned short)(vw.z >> 16);
        Vt[6 * VROW + i] = (i < Nu) ? 0x3F80u : 0u;  // ones row (denominator)
    }
    __syncthreads();

    const int lane = tid & 63, wid = tid >> 6;
    const int s0 = rowbase + wid * 16;
    if (s0 >= Nu) return;  // tail waves; no barriers below
    const int r15 = lane & 15, g = lane >> 4;
    const int sidx = s0 + r15;
    const int srow = rowl[(size_t)b * SEQ + (sidx < Nu ? sidx : Nu - 1)];

    // Q' projection for compacted row srow (4 lane-copies per row)
    float qq[DIM];
    {
        const float2* xp =
            reinterpret_cast<const float2*>(X + ((size_t)b * SEQ + srow) * DIM);
        float2 x01 = xp[0], x23 = xp[1], x45 = xp[2];
        float x[DIM] = {x01.x, x01.y, x23.x, x23.y, x45.x, x45.y};
#pragma unroll
        for (int r = 0; r < DIM; ++r) {
            float q = bq[r];
#pragma unroll
            for (int c = 0; c < DIM; ++c) q = fmaf(Wq[r * DIM + c], x[c], q);
            qq[r] = q;  // compacted rows are all unmasked
        }
    }
    FragU qf;
    qf.u.x = (g == 0) ? pkh(qq[0], qq[1]) : (g == 1) ? pkh(qq[4], qq[5]) : 0u;
    qf.u.y = (g == 0) ? pkh(qq[2], qq[3]) : (g == 1) ? pkh(1.0f, 0.0f) : 0u;

    const f32x4 zero4 = {0.0f, 0.0f, 0.0f, 0.0f};
    // TWO independent PV accumulator chains (even/odd t-tiles) so consecutive
    // QK->exp->PV sequences interleave instead of serializing on one acc.
    // Final acc = acc0 + acc1 (absolute-exp2 partials sum exactly).
    f32x4 acc0 = zero4, acc1 = zero4;
    {
        const int dcl = (r15 < 6) ? r15 : 6;
        int kidx = r15 * 8 + (g & 1) * 4;
        int vidx = dcl * VROW + g * 4;
        const int nchunk = NTC >> (4 + 3);  // tiles/CH
        for (int c = 0; c < nchunk; ++c) {
            half4F kf[CH];
            bf16x4 vf[CH];
#pragma unroll
            for (int u = 0; u < CH; ++u) {
                kf[u] = *reinterpret_cast<const half4F*>(&Ksm[kidx + u * 128]);
                vf[u] = *reinterpret_cast<const bf16x4*>(&Vt[vidx + u * 16]);
            }
#pragma unroll
            for (int u = 0; u < CH; u += 2) {
                f32x4 d0 = __builtin_amdgcn_mfma_f32_16x16x16f16(kf[u], qf.h, zero4, 0, 0, 0);
                f32x4 d1 = __builtin_amdgcn_mfma_f32_16x16x16f16(kf[u + 1], qf.h, zero4, 0, 0, 0);
                FragU p0, p1;
                p0.u.x = pkbf_trunc(__builtin_amdgcn_exp2f(d0[0]),
                                    __builtin_amdgcn_exp2f(d0[1]));
                p0.u.y = pkbf_trunc(__builtin_amdgcn_exp2f(d0[2]),
                                    __builtin_amdgcn_exp2f(d0[3]));
                p1.u.x = pkbf_trunc(__builtin_amdgcn_exp2f(d1[0]),
                                    __builtin_amdgcn_exp2f(d1[1]));
                p1.u.y = pkbf_trunc(__builtin_amdgcn_exp2f(d1[2]),
                                    __builtin_amdgcn_exp2f(d1[3]));
                acc0 = mfma_bf16_(p0.b, vf[u], acc0);
                acc1 = mfma_bf16_(p1.b, vf[u + 1], acc1);
            }
            kidx += CH * 128;
            vidx += CH * 16;
        }
    }
    const f32x4 acc = acc0 + acc1;

    // epilogue: numerators / denominator; scatter to original rows
    const int srcl = (lane & 48) | 6;
#pragma unroll
    for (int r = 0; r < 4; ++r) {
        const float dnm = __shfl(acc[r], srcl);
        const float val = acc[r] * __builtin_amdgcn_rcpf(dnm);
        const int oidx = s0 + g * 4 + r;
        if (r15 < 6 && oidx < Nu) {
            const int orow = rowl[(size_t)b * SEQ + oidx];
            out[((size_t)b * SEQ + orow) * DIM + r15] = val;
        }
    }
}

extern "C" void kernel_launch(void* const* d_in, const int* in_sizes, int n_in,
                              void* d_out, int out_size, void* d_ws, size_t ws_size,
                              hipStream_t stream) {
    const float* X  = (const float*)d_in[0];
    const int* mask = (const int*)d_in[1];
    const float* Wq = (const float*)d_in[2];
    const float* bq = (const float*)d_in[3];
    const float* Wk = (const float*)d_in[4];
    const float* bk = (const float*)d_in[5];
    const float* Wv = (const float*)d_in[6];
    const float* bv = (const float*)d_in[7];
    float* out = (float*)d_out;

    const int B = in_sizes[0] / (SEQ * DIM);

    __fp16* Kc = (__fp16*)d_ws;                                          // B*SEQ*8
    unsigned short* Vc = (unsigned short*)(Kc + (size_t)B * SEQ * 8);    // B*SEQ*8
    unsigned short* rowl = Vc + (size_t)B * SEQ * 8;                     // B*SEQ
    float* vsumP = (float*)(rowl + (size_t)B * SEQ);                     // B*NSEG*8
    int* nuArr = (int*)(vsumP + (size_t)B * NSEG * 8);                   // B

    prep<<<dim3(B * NSEG), 256, 0, stream>>>(X, mask, Wk, bk, Wv, bv,
                                             Kc, Vc, rowl, vsumP, nuArr);
    attn_mfma<<<dim3(B * 16), 512, 0, stream>>>(X, mask, Wq, bq, Kc, Vc, rowl,
                                                vsumP, nuArr, out);
}